// Round 11
// baseline (218.228 us; speedup 1.0000x reference)
//
#include <hip/hip_runtime.h>

typedef __bf16 bf16x8 __attribute__((ext_vector_type(8)));
typedef float f32x4 __attribute__((ext_vector_type(4)));
typedef unsigned short u16x8 __attribute__((ext_vector_type(8)));
typedef unsigned short u16x4 __attribute__((ext_vector_type(4)));

#define MFMA16(a, b, c) __builtin_amdgcn_mfma_f32_16x16x32_bf16((a), (b), (c), 0, 0, 0)

__device__ __forceinline__ float bf2f(unsigned short u) {
  union { unsigned int i; float f; } v; v.i = ((unsigned int)u) << 16; return v.f;
}
__device__ __forceinline__ unsigned short f2bf(float f) {
  union { float f; unsigned int i; } v; v.f = f;
  unsigned int u = v.i;
  u += 0x7fffu + ((u >> 16) & 1u);   // RNE
  return (unsigned short)(u >> 16);
}

// ---------------------------------------------------------------------------
// MFMA GEMM: C[M x N] = A[M x 1024] @ B[1024 x N] + bias[N], fp32 accum.
// A: fp32 (a_bf16=0) or bf16 (a_bf16=1). B/bias: fp32. LDS tiles bf16.
// mode 0: N=3072, scatter Q[b,h,s,d], K[b,h,s,d], V[b,h,d,s] (transposed), bf16.
// mode 1: N=1024, store FP32 to OF[m*1024+n]   <-- the round-10 fix.
// Block 256 (4 waves), tile 64x64, BK=32. Wave w owns cols [16w,16w+16).
// Fragment choreography = ref-verified m92/m97 lineage; cross-validated
// against pure-VALU GEMM (R3==R4 bit-identical absmax).
// ---------------------------------------------------------------------------
__global__ __launch_bounds__(256) void gemm_kernel(
    const void* __restrict__ A, const float* __restrict__ B,
    const float* __restrict__ bias,
    unsigned short* __restrict__ O0, unsigned short* __restrict__ O1,
    unsigned short* __restrict__ O2, float* __restrict__ OF,
    int N, int mode, int a_bf16) {
  __shared__ __align__(16) unsigned short As[64][40];   // pad 32->40
  __shared__ __align__(16) unsigned short Bs[32][72];   // pad 64->72

  const int K = 1024;
  int tid = threadIdx.x;
  int lane = tid & 63, wave = tid >> 6, quad = lane >> 4, l16 = lane & 15;
  int m0 = blockIdx.x * 64, n0 = blockIdx.y * 64;

  int ar = tid >> 2, ac = (tid & 3) * 8;   // A stage: 64 rows x 32 cols
  int br = tid >> 3, bc = (tid & 7) * 8;   // B stage: 32 rows x 64 cols

  const unsigned short* Ag16 = (const unsigned short*)A + (size_t)(m0 + ar) * K + ac;
  const float*          Ag32 = (const float*)A + (size_t)(m0 + ar) * K + ac;
  const float*          Bg32 = B + (size_t)br * N + n0 + bc;

  f32x4 zero = {0.f, 0.f, 0.f, 0.f};
  f32x4 acc[4];
#pragma unroll
  for (int i = 0; i < 4; ++i) acc[i] = zero;

  for (int k0 = 0; k0 < K; k0 += 32) {
    if (a_bf16) {
      *(u16x8*)&As[ar][ac] = *(const u16x8*)(Ag16 + k0);
    } else {
      f32x4 f0 = *(const f32x4*)(Ag32 + k0);
      f32x4 f1 = *(const f32x4*)(Ag32 + k0 + 4);
      u16x8 t;
#pragma unroll
      for (int j = 0; j < 4; ++j) { t[j] = f2bf(f0[j]); t[4 + j] = f2bf(f1[j]); }
      *(u16x8*)&As[ar][ac] = t;
    }
    {
      f32x4 f0 = *(const f32x4*)(Bg32 + (size_t)k0 * N);
      f32x4 f1 = *(const f32x4*)(Bg32 + (size_t)k0 * N + 4);
      u16x8 t;
#pragma unroll
      for (int j = 0; j < 4; ++j) { t[j] = f2bf(f0[j]); t[4 + j] = f2bf(f1[j]); }
      *(u16x8*)&Bs[br][bc] = t;
    }
    __syncthreads();
    bf16x8 bfrag;
    {
      union { unsigned short u[8]; bf16x8 v; } t;
#pragma unroll
      for (int j = 0; j < 8; ++j) t.u[j] = Bs[quad * 8 + j][wave * 16 + l16];
      bfrag = t.v;
    }
#pragma unroll
    for (int mt = 0; mt < 4; ++mt) {
      bf16x8 af = __builtin_bit_cast(bf16x8, *(const u16x8*)&As[mt * 16 + l16][quad * 8]);
      acc[mt] = MFMA16(af, bfrag, acc[mt]);
    }
    __syncthreads();
  }

  int n = n0 + wave * 16 + l16;     // C-layout: col = lane&15
  float bv = bias[n];

  if (mode == 0) {
    int seg = n >> 10;              // 0=q 1=k 2=v (uniform per block)
    int c = n & 1023, hh = c >> 6, d = c & 63;
#pragma unroll
    for (int mt = 0; mt < 4; ++mt) {
      int mbase = m0 + mt * 16 + quad * 4;
      int b = mbase >> 11, s = mbase & 2047;
      if (seg == 2) {
        u16x4 pk;
#pragma unroll
        for (int r = 0; r < 4; ++r) pk[r] = f2bf(acc[mt][r] + bv);
        *(u16x4*)&O2[((size_t)((b << 4) + hh) * 64 + d) * 2048 + s] = pk;   // V[b,h,d,s]
      } else {
        unsigned short* O = (seg == 0) ? O0 : O1;
#pragma unroll
        for (int r = 0; r < 4; ++r)
          O[((size_t)((b << 4) + hh) * 2048 + (s + r)) * 64 + d] = f2bf(acc[mt][r] + bv);
      }
    }
  } else {
#pragma unroll
    for (int mt = 0; mt < 4; ++mt)
#pragma unroll
      for (int r = 0; r < 4; ++r) {
        int m = m0 + mt * 16 + quad * 4 + r;
        OF[(size_t)m * 1024 + n] = acc[mt][r] + bv;    // FP32 output
      }
  }
}

// ---------------------------------------------------------------------------
// MFMA windowed flash attention. Query i attends keys j in [i, i+255], j<S.
// Block = (b, h, 64-query tile); 4 waves; wave w owns queries [16w, 16w+16).
// 10 steps of 32 keys; wave w active for 9. Cross-validated vs VALU attention
// (R2==R3 bit-identical absmax).
// ---------------------------------------------------------------------------
__global__ __launch_bounds__(256) void attn_kernel(
    const unsigned short* __restrict__ Q, const unsigned short* __restrict__ Kq,
    const unsigned short* __restrict__ Vt, unsigned short* __restrict__ AO) {
  __shared__ __align__(16) unsigned short Ks[32][72];      // [key][d]
  __shared__ __align__(16) unsigned short Vs[64][40];      // [d][key]
  __shared__ __align__(16) unsigned short Ps[4][16][40];   // per-wave P: [q][key]

  int bid = blockIdx.x;
  int qblk = bid & 31, h = (bid >> 5) & 15, b = bid >> 9;
  int q0 = qblk * 64;
  int tid = threadIdx.x, lane = tid & 63, wave = tid >> 6, quad = lane >> 4, l16 = lane & 15;

  const unsigned short* Qb = Q + (size_t)(((b << 4) + h) * 2048) * 64;
  const unsigned short* Kb = Kq + (size_t)(((b << 4) + h) * 2048) * 64;
  const unsigned short* Vb = Vt + (size_t)(((b << 4) + h) * 64) * 2048;

  int qrow = q0 + wave * 16 + l16;   // A-frag row m = lane&15
  bf16x8 qf0 = __builtin_bit_cast(bf16x8, *(const u16x8*)&Qb[(size_t)qrow * 64 + quad * 8]);
  bf16x8 qf1 = __builtin_bit_cast(bf16x8, *(const u16x8*)&Qb[(size_t)qrow * 64 + 32 + quad * 8]);

  float mrow[4], lrow[4];
  f32x4 zero = {0.f, 0.f, 0.f, 0.f};
  f32x4 o[4];
#pragma unroll
  for (int i = 0; i < 4; ++i) o[i] = zero;
#pragma unroll
  for (int r = 0; r < 4; ++r) { mrow[r] = -1e30f; lrow[r] = 0.f; }

  const float SCALE = 0.125f;  // 64^-0.5
  int pstart = (wave >= 2) ? 1 : 0;
  int pend = pstart + 8;

  int ki = tid >> 3, kc = (tid & 7) * 8;   // K stage: 32 keys x 64 d
  int vd = tid >> 2, vc = (tid & 3) * 8;   // V stage: 64 d x 32 keys

  for (int p = 0; p < 10; ++p) {
    int kbase = q0 + p * 32;
    {
      int s = kbase + ki; s = s > 2047 ? 2047 : s;   // clamp; masked later
      *(u16x8*)&Ks[ki][kc] = *(const u16x8*)&Kb[(size_t)s * 64 + kc];
    }
    if (kbase + vc + 7 <= 2047) {
      *(u16x8*)&Vs[vd][vc] = *(const u16x8*)&Vb[(size_t)vd * 2048 + kbase + vc];
    } else {
#pragma unroll
      for (int j = 0; j < 8; ++j) {
        int s = kbase + vc + j; s = s > 2047 ? 2047 : s;
        Vs[vd][vc + j] = Vb[(size_t)vd * 2048 + s];
      }
    }
    __syncthreads();

    if (p >= pstart && p <= pend) {
      // S = Q K^T : B-frag = K[key=lane&15][d=quad*8+j]
      f32x4 sc[2];
#pragma unroll
      for (int t = 0; t < 2; ++t) {
        bf16x8 kf0 = __builtin_bit_cast(bf16x8, *(const u16x8*)&Ks[t * 16 + l16][quad * 8]);
        bf16x8 kf1 = __builtin_bit_cast(bf16x8, *(const u16x8*)&Ks[t * 16 + l16][32 + quad * 8]);
        f32x4 z = zero;
        z = MFMA16(qf0, kf0, z);
        z = MFMA16(qf1, kf1, z);
        sc[t] = z;
      }
      float sv[2][4];
#pragma unroll
      for (int t = 0; t < 2; ++t)
#pragma unroll
        for (int r = 0; r < 4; ++r) {
          int kg = kbase + t * 16 + l16;
          int qg = q0 + wave * 16 + quad * 4 + r;
          bool valid = (kg >= qg) && (kg <= qg + 255) && (kg < 2048);
          sv[t][r] = valid ? sc[t][r] * SCALE : -1e30f;
        }
#pragma unroll
      for (int r = 0; r < 4; ++r) {
        float v = fmaxf(sv[0][r], sv[1][r]);
        v = fmaxf(v, __shfl_xor(v, 1));
        v = fmaxf(v, __shfl_xor(v, 2));
        v = fmaxf(v, __shfl_xor(v, 4));
        v = fmaxf(v, __shfl_xor(v, 8));
        float mnew = fmaxf(mrow[r], v);
        float alpha = __expf(mrow[r] - mnew);
        mrow[r] = mnew;
        float p0 = __expf(sv[0][r] - mnew);
        float p1 = __expf(sv[1][r] - mnew);
        p0 = (sv[0][r] > -5e29f) ? p0 : 0.f;
        p1 = (sv[1][r] > -5e29f) ? p1 : 0.f;
        float rs = p0 + p1;
        rs += __shfl_xor(rs, 1);
        rs += __shfl_xor(rs, 2);
        rs += __shfl_xor(rs, 4);
        rs += __shfl_xor(rs, 8);
        lrow[r] = lrow[r] * alpha + rs;
#pragma unroll
        for (int nt = 0; nt < 4; ++nt) o[nt][r] *= alpha;
        Ps[wave][quad * 4 + r][l16] = f2bf(p0);
        Ps[wave][quad * 4 + r][16 + l16] = f2bf(p1);
      }
      __threadfence_block();
      bf16x8 pf = __builtin_bit_cast(bf16x8, *(const u16x8*)&Ps[wave][l16][quad * 8]);
#pragma unroll
      for (int nt = 0; nt < 4; ++nt) {
        bf16x8 vf = __builtin_bit_cast(bf16x8, *(const u16x8*)&Vs[nt * 16 + l16][quad * 8]);
        o[nt] = MFMA16(pf, vf, o[nt]);
      }
    }
    __syncthreads();
  }

  unsigned short* dst = AO + ((size_t)(b * 2048 + q0 + wave * 16) * 1024) + h * 64;
#pragma unroll
  for (int nt = 0; nt < 4; ++nt)
#pragma unroll
    for (int r = 0; r < 4; ++r) {
      int qq = quad * 4 + r;
      dst[(size_t)qq * 1024 + nt * 16 + l16] = f2bf(o[nt][r] / lrow[r]);
    }
}

extern "C" void kernel_launch(void* const* d_in, const int* in_sizes, int n_in,
                              void* d_out, int out_size, void* d_ws, size_t ws_size,
                              hipStream_t stream) {
  const void* x = d_in[0];
  const float* W_qkv = (const float*)d_in[1];
  const float* b_qkv = (const float*)d_in[2];
  const float* W_out = (const float*)d_in[3];
  const float* b_out = (const float*)d_in[4];
  float* out = (float*)d_out;               // FP32 output (round-10 finding)

  unsigned short* ws = (unsigned short*)d_ws;
  unsigned short* Qw = ws;                  // [b,h,s,d] bf16
  unsigned short* Kw = ws + 4194304;        // [b,h,s,d] bf16
  unsigned short* Vw = ws + 8388608;        // [b,h,d,s] bf16 (transposed)
  unsigned short* AO = ws + 12582912;       // [b,s,h*64+d] bf16

  dim3 blk(256);
  gemm_kernel<<<dim3(64, 48), blk, 0, stream>>>(x, W_qkv, b_qkv, Qw, Kw, Vw, nullptr, 3072, 0, 0);
  attn_kernel<<<dim3(1024), blk, 0, stream>>>(Qw, Kw, Vw, AO);
  gemm_kernel<<<dim3(64, 16), blk, 0, stream>>>(AO, W_out, b_out, nullptr, nullptr, nullptr, out, 1024, 1, 1);
}